// Round 3
// baseline (353.747 us; speedup 1.0000x reference)
//
#include <hip/hip_runtime.h>
#include <hip/hip_bf16.h>

// B=4, S=2048, C=1024 attention block, fp32 in/out.
// fp16 MFMA (16x16x32) GEMMs, fp32 accumulate, 128xTN tiles (TN=64 -> grid
// 1024 = 4 blocks/CU on all GEMMs), global_load_lds(16B) staging with XOR
// bank swizzle, XCD-aware block remap. V projection writes V^T directly.

typedef _Float16 half8 __attribute__((ext_vector_type(8)));
typedef _Float16 half4 __attribute__((ext_vector_type(4)));
typedef float f32x4 __attribute__((ext_vector_type(4)));

#define AS1(p) ((const __attribute__((address_space(1))) void*)(p))
#define AS3(p) ((__attribute__((address_space(3))) void*)(p))

// ---------------- fp32 -> fp16 convert, 3 tensors per launch ----------------
__global__ __launch_bounds__(256) void cvt3_f32_f16(
    const float* __restrict__ s0, const float* __restrict__ s1,
    const float* __restrict__ s2, _Float16* __restrict__ d0,
    _Float16* __restrict__ d1, _Float16* __restrict__ d2, int n) {
    const float* s = blockIdx.y == 0 ? s0 : blockIdx.y == 1 ? s1 : s2;
    _Float16* d = blockIdx.y == 0 ? d0 : blockIdx.y == 1 ? d1 : d2;
    int i = (blockIdx.x * 256 + threadIdx.x) * 8;
    if (i >= n) return;
    float4 a = *(const float4*)(s + i);
    float4 b = *(const float4*)(s + i + 4);
    half8 h;
    h[0] = (_Float16)a.x; h[1] = (_Float16)a.y; h[2] = (_Float16)a.z; h[3] = (_Float16)a.w;
    h[4] = (_Float16)b.x; h[5] = (_Float16)b.y; h[6] = (_Float16)b.z; h[7] = (_Float16)b.w;
    *(half8*)(d + i) = h;
}

// ---------------- NT GEMM: C[m,n] = scale*sum_k A[m,k]*Bt[n,k] (+bias[n]) ----
// Block tile 128 x TN, BK=32, 4 waves (2x2), wave tile 64 x (TN/2).
// LDS [rows][32] halves, XOR chunk swizzle (2-way/free). All grids 1024.
// TROUT: write output transposed per-batch (Vt[b][col][row&2047]) for B=4,S=2048.
template <int K, int TN, bool BIAS, bool F16OUT, bool TROUT, int GYS>
__global__ __launch_bounds__(256, 2)
void gemm_nt(const _Float16* __restrict__ A, const _Float16* __restrict__ Bt,
             const float* __restrict__ bias, void* __restrict__ Cout,
             int N, float scale, long sA, long sB, long sC) {
    constexpr int JN = TN / 32;           // 16-col tiles per wave (2 or 4)
    constexpr int SLABS = (128 + TN) / 16;
    __shared__ _Float16 Asm[128 * 32] __attribute__((aligned(16)));
    __shared__ _Float16 Bsm[TN * 32] __attribute__((aligned(16)));
    const int tid = threadIdx.x;
    const int lane = tid & 63;
    const int wave = tid >> 6;

    // XCD-aware remap: xcd = lin&7; each XCD owns 8 contiguous row_ids x all x.
    const int lin = blockIdx.x;
    const int g = lin & 7;
    const int s = lin >> 3;
    const int xt = s & 15;                       // GXS = 4 (16 x-tiles)
    const int row_id = g * 8 + (s >> 4);         // R = 8
    const int yt = row_id & ((1 << GYS) - 1);
    const long zb = row_id >> GYS;
    const int m0 = yt * 128;
    const int n0 = xt * TN;

    A += zb * sA;
    Bt += zb * sB;

    const int srow = lane >> 2;                                  // 0..15
    const int csw = (((lane & 3) ^ ((srow >> 1) & 3)) << 3);     // swizzled src chunk (halves)
    const int quad = lane >> 4;                                  // 0..3
    const int l16 = lane & 15;
    const int aswz = ((quad ^ ((l16 >> 1) & 3)) << 3);           // read-side swizzle (halves)
    const int wm = (wave >> 1) << 6;
    const int wn = (wave & 1) * (TN >> 1);

    f32x4 acc[4][JN];
#pragma unroll
    for (int i = 0; i < 4; i++)
#pragma unroll
        for (int j = 0; j < JN; j++)
#pragma unroll
            for (int r = 0; r < 4; r++) acc[i][j][r] = 0.0f;

    const _Float16* Abase = A + (long)m0 * K;
    const _Float16* Bbase = Bt + (long)n0 * K;

    for (int k0 = 0; k0 < K; k0 += 32) {
        __syncthreads();  // previous iteration's LDS reads complete
#pragma unroll
        for (int t = wave; t < SLABS; t += 4) {   // wave-uniform slab ids
            if (t < 8) {
                __builtin_amdgcn_global_load_lds(
                    AS1(Abase + (long)(t * 16 + srow) * K + k0 + csw),
                    AS3(Asm + t * 512), 16, 0, 0);
            } else {
                __builtin_amdgcn_global_load_lds(
                    AS1(Bbase + (long)((t - 8) * 16 + srow) * K + k0 + csw),
                    AS3(Bsm + (t - 8) * 512), 16, 0, 0);
            }
        }
        __syncthreads();  // staging drained

        half8 af[4], bf[JN];
#pragma unroll
        for (int i = 0; i < 4; i++)
            af[i] = *(const half8*)(Asm + (wm + i * 16 + l16) * 32 + aswz);
#pragma unroll
        for (int j = 0; j < JN; j++)
            bf[j] = *(const half8*)(Bsm + (wn + j * 16 + l16) * 32 + aswz);
#pragma unroll
        for (int i = 0; i < 4; i++)
#pragma unroll
            for (int j = 0; j < JN; j++)
                acc[i][j] = __builtin_amdgcn_mfma_f32_16x16x32_f16(af[i], bf[j], acc[i][j], 0, 0, 0);
    }

    // Epilogue: C/D layout col=lane&15, row=quad*4+reg (m89/m121-128 verified).
#pragma unroll
    for (int i = 0; i < 4; i++) {
        const int row = m0 + wm + i * 16 + quad * 4;
#pragma unroll
        for (int j = 0; j < JN; j++) {
            const int col = n0 + wn + j * 16 + l16;
            const float badd = BIAS ? bias[col] : 0.0f;
            if constexpr (TROUT) {
                // Vt[b][col][row&2047], 4 consecutive s-elements per lane (8B aligned)
                const long b = row >> 11;
                const int sl = row & 2047;
                half4 h;
#pragma unroll
                for (int r = 0; r < 4; r++) h[r] = (_Float16)(acc[i][j][r] * scale + badd);
                *(half4*)((_Float16*)Cout + b * 2097152 + (long)col * 2048 + sl) = h;
            } else {
#pragma unroll
                for (int r = 0; r < 4; r++) {
                    float v = acc[i][j][r] * scale + badd;
                    if constexpr (F16OUT) {
                        ((_Float16*)Cout + zb * sC)[(long)(row + r) * N + col] = (_Float16)v;
                    } else {
                        ((float*)Cout + zb * sC)[(long)(row + r) * N + col] = v;
                    }
                }
            }
        }
    }
}

// ---------------- row softmax: fp16 scores [8192][2048] -> fp16 probs --------
__global__ __launch_bounds__(256) void softmax_f16(const _Float16* __restrict__ S,
                                                   _Float16* __restrict__ P) {
    const long row = blockIdx.x;
    const int t = threadIdx.x;
    const int wave = t >> 6, lane = t & 63;
    half8 h = ((const half8*)(S + row * 2048))[t];
    float v[8];
#pragma unroll
    for (int j = 0; j < 8; j++) v[j] = (float)h[j];
    float m = v[0];
#pragma unroll
    for (int j = 1; j < 8; j++) m = fmaxf(m, v[j]);
#pragma unroll
    for (int off = 32; off > 0; off >>= 1) m = fmaxf(m, __shfl_xor(m, off, 64));
    __shared__ float redm[4], reds[4];
    if (lane == 0) redm[wave] = m;
    __syncthreads();
    m = fmaxf(fmaxf(redm[0], redm[1]), fmaxf(redm[2], redm[3]));
    float sum = 0.0f;
#pragma unroll
    for (int j = 0; j < 8; j++) { v[j] = __expf(v[j] - m); sum += v[j]; }
#pragma unroll
    for (int off = 32; off > 0; off >>= 1) sum += __shfl_xor(sum, off, 64);
    if (lane == 0) reds[wave] = sum;
    __syncthreads();
    sum = (reds[0] + reds[1]) + (reds[2] + reds[3]);
    const float inv = 1.0f / sum;
    half8 o;
#pragma unroll
    for (int j = 0; j < 8; j++) o[j] = (_Float16)(v[j] * inv);
    ((half8*)(P + row * 2048))[t] = o;
}

// ---------------- launch ----------------------------------------------------
extern "C" void kernel_launch(void* const* d_in, const int* in_sizes, int n_in,
                              void* d_out, int out_size, void* d_ws, size_t ws_size,
                              hipStream_t stream) {
    constexpr int B = 4, S = 2048, C = 1024;
    constexpr long XSZ = (long)B * S * C;   // 8388608
    constexpr long WSZ = (long)C * C;       // 1048576

    const float* query = (const float*)d_in[0];
    const float* key   = (const float*)d_in[1];
    const float* value = (const float*)d_in[2];
    const float* Wq = (const float*)d_in[3];
    const float* bq = (const float*)d_in[4];
    const float* Wk = (const float*)d_in[5];
    const float* bk = (const float*)d_in[6];
    const float* Wv = (const float*)d_in[7];
    const float* bv = (const float*)d_in[8];
    float* out = (float*)d_out;
    char* ws = (char*)d_ws;

    // Workspace (bytes): Region0 [0, 56623104): Xq,Xk,Xv,Wqh,Wkh,Wvh (dead
    // after projections) -> reused for fp16 scores (33554432 B).
    // Region1 [73400320): Qh,Kh (dead after QK^T) -> reused for fp16 attn.
    // Region2 [106954752): Vt (written transposed by V projection).
    _Float16* Xq  = (_Float16*)(ws + 0);
    _Float16* Xk  = (_Float16*)(ws + XSZ * 2);
    _Float16* Xv  = (_Float16*)(ws + 2 * XSZ * 2);
    _Float16* Wqh = (_Float16*)(ws + 3 * XSZ * 2);
    _Float16* Wkh = (_Float16*)(ws + 3 * XSZ * 2 + WSZ * 2);
    _Float16* Wvh = (_Float16*)(ws + 3 * XSZ * 2 + 2 * WSZ * 2);
    _Float16* scores = (_Float16*)(ws + 0);
    _Float16* Qh  = (_Float16*)(ws + 73400320);
    _Float16* Kh  = (_Float16*)(ws + 73400320 + XSZ * 2);
    _Float16* attn = (_Float16*)(ws + 73400320);
    _Float16* Vt  = (_Float16*)(ws + 106954752);
    if (ws_size < 123731968) return;

    // 1) convert inputs + weights to fp16 (2 launches)
    cvt3_f32_f16<<<dim3(XSZ / 2048, 3), 256, 0, stream>>>(query, key, value, Xq, Xk, Xv, (int)XSZ);
    cvt3_f32_f16<<<dim3(WSZ / 2048, 3), 256, 0, stream>>>(Wq, Wk, Wv, Wqh, Wkh, Wvh, (int)WSZ);

    // 2) projections: M=8192 (64 y-tiles), N=1024 (16 x-tiles of 64), K=1024.
    //    grid 1024 = 4 blocks/CU. GYS=6 (z collapses to 0).
    gemm_nt<1024, 64, true, true, false, 6><<<1024, 256, 0, stream>>>(Xq, Wqh, bq, Qh, C, 1.0f, 0, 0, 0);
    gemm_nt<1024, 64, true, true, false, 6><<<1024, 256, 0, stream>>>(Xk, Wkh, bk, Kh, C, 1.0f, 0, 0, 0);
    //    V projection writes Vt[b][d][s] directly (TROUT).
    gemm_nt<1024, 64, true, true, true, 6><<<1024, 256, 0, stream>>>(Xv, Wvh, bv, Vt, C, 1.0f, 0, 0, 0);

    // 3) scores = Qh @ Kh^T / 32, fp16 out. 128x128 tiles: 16x16 x-y, z=4 -> 1024.
    gemm_nt<1024, 128, false, true, false, 4><<<1024, 256, 0, stream>>>(
        Qh, Kh, nullptr, scores, S, 0.03125f, (long)S * C, (long)S * C, (long)S * S);

    // 4) row softmax (fp16 in/out)
    softmax_f16<<<B * S, 256, 0, stream>>>(scores, attn);

    // 5) out = attn @ Vt^T. 128x64 tiles: M=2048 (16 y), N=1024 (16 x), z=4 -> 1024.
    gemm_nt<2048, 64, false, false, false, 4><<<1024, 256, 0, stream>>>(
        attn, Vt, nullptr, out, C, 1.0f, (long)S * S, (long)C * S, (long)S * C);
}

// Round 4
// 308.194 us; speedup vs baseline: 1.1478x; 1.1478x over previous
//
#include <hip/hip_runtime.h>
#include <hip/hip_bf16.h>

// B=4, S=2048, C=1024 attention block, fp32 in/out.
// fp16 MFMA (16x16x32), fp32 accumulate. 128x128 tiles, BK=64 (32 KB LDS,
// 2 k-substeps per barrier -> 32 MFMA/wave/iter), global_load_lds(16B)
// staging, XOR-chunk LDS swizzle (2-way, free), XCD-aware block remap.
// All 3 projections in ONE dispatch; V-projection writes V^T directly.

typedef _Float16 half8 __attribute__((ext_vector_type(8)));
typedef _Float16 half4 __attribute__((ext_vector_type(4)));
typedef float f32x4 __attribute__((ext_vector_type(4)));

#define AS1(p) ((const __attribute__((address_space(1))) void*)(p))
#define AS3(p) ((__attribute__((address_space(3))) void*)(p))

// ---------------- fp32 -> fp16 convert, 3 tensors per launch ----------------
__global__ __launch_bounds__(256) void cvt3_f32_f16(
    const float* __restrict__ s0, const float* __restrict__ s1,
    const float* __restrict__ s2, _Float16* __restrict__ d0,
    _Float16* __restrict__ d1, _Float16* __restrict__ d2, int n) {
    const float* s = blockIdx.y == 0 ? s0 : blockIdx.y == 1 ? s1 : s2;
    _Float16* d = blockIdx.y == 0 ? d0 : blockIdx.y == 1 ? d1 : d2;
    int i = (blockIdx.x * 256 + threadIdx.x) * 8;
    if (i >= n) return;
    float4 a = *(const float4*)(s + i);
    float4 b = *(const float4*)(s + i + 4);
    half8 h;
    h[0] = (_Float16)a.x; h[1] = (_Float16)a.y; h[2] = (_Float16)a.z; h[3] = (_Float16)a.w;
    h[4] = (_Float16)b.x; h[5] = (_Float16)b.y; h[6] = (_Float16)b.z; h[7] = (_Float16)b.w;
    *(half8*)(d + i) = h;
}

// ---------------- NT GEMM, 128x128 tile, BK=64 ------------------------------
// C[m,n] = scale*sum_k A[m,k]*Bt[n,k] (+bias[n]).
// LDS rows = 64 halves (128 B = 8 x 16B chunks); chunk swizzle: logical chunk
// q of row r stored at q^(r&7). Staging: lane -> row lane>>3, logical chunk
// (lane&7)^((lane>>3)&7)  => 8 lanes cover one full 128B row (coalesced).
// Block remap: xcd = lin&7; each XCD owns R contiguous row_ids x all NX x-tiles.
// PROJ3: row_id's high bits select tensor tz in {0,1,2}=Q,K,V; V writes C^T.
template <int K, int NX_SH, int R, int NYT_SH, bool BIAS, bool F16OUT, bool PROJ3>
__global__ __launch_bounds__(256, 2)
void gemm_nt(const _Float16* __restrict__ A, const _Float16* __restrict__ Bt,
             const float* __restrict__ b0, const float* __restrict__ b1,
             const float* __restrict__ b2, void* __restrict__ Cout,
             _Float16* __restrict__ VtOut, int N, float scale,
             long sA, long sB, long sC) {
    __shared__ _Float16 Asm[128 * 64] __attribute__((aligned(16)));
    __shared__ _Float16 Bsm[128 * 64] __attribute__((aligned(16)));
    const int tid = threadIdx.x;
    const int lane = tid & 63;
    const int wave = tid >> 6;

    const int lin = blockIdx.x;
    const int g = lin & 7;
    const int s = lin >> 3;
    const int xt = s & ((1 << NX_SH) - 1);
    const int row_id = g * R + (s >> NX_SH);
    const int yt = row_id & ((1 << NYT_SH) - 1);
    const int tz = row_id >> NYT_SH;     // PROJ3: tensor id; else: batch id
    const int m0 = yt * 128;
    const int n0 = xt * 128;

    const float* bias = nullptr;
    if constexpr (PROJ3) {
        A += (long)tz * 8388608;         // Xq,Xk,Xv contiguous
        Bt += (long)tz * 1048576;        // Wqh,Wkh,Wvh contiguous
        bias = tz == 0 ? b0 : tz == 1 ? b1 : b2;
    } else {
        A += (long)tz * sA;
        Bt += (long)tz * sB;
    }

    const int srow8 = lane >> 3;                                   // 0..7
    const int sq = ((lane & 7) ^ srow8) << 3;                      // staged logical chunk (halves)
    const int quad = lane >> 4;
    const int l16 = lane & 15;
    const int wm = (wave >> 1) << 6;
    const int wn = (wave & 1) << 6;
    // fragment LDS half-offsets for k-substeps 0,1 (i-tile adds i*1024)
    const int fa0 = (wm + l16) * 64 + (((0 * 4 + quad) ^ (l16 & 7)) << 3);
    const int fa1 = (wm + l16) * 64 + (((1 * 4 + quad) ^ (l16 & 7)) << 3);
    const int fb0 = (wn + l16) * 64 + (((0 * 4 + quad) ^ (l16 & 7)) << 3);
    const int fb1 = (wn + l16) * 64 + (((1 * 4 + quad) ^ (l16 & 7)) << 3);

    f32x4 acc[4][4];
#pragma unroll
    for (int i = 0; i < 4; i++)
#pragma unroll
        for (int j = 0; j < 4; j++)
#pragma unroll
            for (int r = 0; r < 4; r++) acc[i][j][r] = 0.0f;

    const _Float16* Abase = A + (long)m0 * K;
    const _Float16* Bbase = Bt + (long)n0 * K;

    for (int k0 = 0; k0 < K; k0 += 64) {
        __syncthreads();  // previous iteration's LDS reads complete
#pragma unroll
        for (int u = 0; u < 8; ++u) {
            const int t = wave + u * 4;  // wave-uniform slab 0..31 (A:0-15, B:16-31)
            if (t < 16) {
                __builtin_amdgcn_global_load_lds(
                    AS1(Abase + (long)(t * 8 + srow8) * K + k0 + sq),
                    AS3(Asm + t * 512), 16, 0, 0);
            } else {
                __builtin_amdgcn_global_load_lds(
                    AS1(Bbase + (long)((t - 16) * 8 + srow8) * K + k0 + sq),
                    AS3(Bsm + (t - 16) * 512), 16, 0, 0);
            }
        }
        __syncthreads();  // staging drained

#pragma unroll
        for (int ks = 0; ks < 2; ++ks) {
            const int ao = ks ? fa1 : fa0;
            const int bo = ks ? fb1 : fb0;
            half8 af[4], bf[4];
#pragma unroll
            for (int i = 0; i < 4; i++) af[i] = *(const half8*)(Asm + ao + i * 1024);
#pragma unroll
            for (int j = 0; j < 4; j++) bf[j] = *(const half8*)(Bsm + bo + j * 1024);
#pragma unroll
            for (int i = 0; i < 4; i++)
#pragma unroll
                for (int j = 0; j < 4; j++)
                    acc[i][j] = __builtin_amdgcn_mfma_f32_16x16x32_f16(af[i], bf[j], acc[i][j], 0, 0, 0);
        }
    }

    // Epilogue: C/D layout col=lane&15, row=quad*4+reg (m89/m121-128 verified).
    const bool trout = PROJ3 && tz == 2;
#pragma unroll
    for (int i = 0; i < 4; i++) {
        const int row = m0 + wm + i * 16 + quad * 4;
#pragma unroll
        for (int j = 0; j < 4; j++) {
            const int col = n0 + wn + j * 16 + l16;
            const float badd = BIAS ? bias[col] : 0.0f;
            if (trout) {
                // Vt[b][col][row&2047]; 4 consecutive s-elems per lane (8B store)
                const long b = row >> 11;
                const int sl = row & 2047;
                half4 h;
#pragma unroll
                for (int r = 0; r < 4; r++) h[r] = (_Float16)(acc[i][j][r] * scale + badd);
                *(half4*)(VtOut + b * 2097152 + (long)col * 2048 + sl) = h;
            } else if constexpr (PROJ3) {
                _Float16* o = (_Float16*)Cout + (long)tz * 8388608;
#pragma unroll
                for (int r = 0; r < 4; r++)
                    o[(long)(row + r) * N + col] = (_Float16)(acc[i][j][r] * scale + badd);
            } else {
#pragma unroll
                for (int r = 0; r < 4; r++) {
                    float v = acc[i][j][r] * scale + badd;
                    if constexpr (F16OUT)
                        ((_Float16*)Cout + (long)tz * sC)[(long)(row + r) * N + col] = (_Float16)v;
                    else
                        ((float*)Cout + (long)tz * sC)[(long)(row + r) * N + col] = v;
                }
            }
        }
    }
}

// ---------------- row softmax: fp16 scores [8192][2048] -> fp16 probs --------
__global__ __launch_bounds__(256) void softmax_f16(const _Float16* __restrict__ S,
                                                   _Float16* __restrict__ P) {
    const long row = blockIdx.x;
    const int t = threadIdx.x;
    const int wave = t >> 6, lane = t & 63;
    half8 h = ((const half8*)(S + row * 2048))[t];
    float v[8];
#pragma unroll
    for (int j = 0; j < 8; j++) v[j] = (float)h[j];
    float m = v[0];
#pragma unroll
    for (int j = 1; j < 8; j++) m = fmaxf(m, v[j]);
#pragma unroll
    for (int off = 32; off > 0; off >>= 1) m = fmaxf(m, __shfl_xor(m, off, 64));
    __shared__ float redm[4], reds[4];
    if (lane == 0) redm[wave] = m;
    __syncthreads();
    m = fmaxf(fmaxf(redm[0], redm[1]), fmaxf(redm[2], redm[3]));
    float sum = 0.0f;
#pragma unroll
    for (int j = 0; j < 8; j++) { v[j] = __expf(v[j] - m); sum += v[j]; }
#pragma unroll
    for (int off = 32; off > 0; off >>= 1) sum += __shfl_xor(sum, off, 64);
    if (lane == 0) reds[wave] = sum;
    __syncthreads();
    sum = (reds[0] + reds[1]) + (reds[2] + reds[3]);
    const float inv = 1.0f / sum;
    half8 o;
#pragma unroll
    for (int j = 0; j < 8; j++) o[j] = (_Float16)(v[j] * inv);
    ((half8*)(P + row * 2048))[t] = o;
}

// ---------------- launch ----------------------------------------------------
extern "C" void kernel_launch(void* const* d_in, const int* in_sizes, int n_in,
                              void* d_out, int out_size, void* d_ws, size_t ws_size,
                              hipStream_t stream) {
    constexpr int B = 4, S = 2048, C = 1024;
    constexpr long XSZ = (long)B * S * C;   // 8388608
    constexpr long WSZ = (long)C * C;       // 1048576

    const float* query = (const float*)d_in[0];
    const float* key   = (const float*)d_in[1];
    const float* value = (const float*)d_in[2];
    const float* Wq = (const float*)d_in[3];
    const float* bq = (const float*)d_in[4];
    const float* Wk = (const float*)d_in[5];
    const float* bk = (const float*)d_in[6];
    const float* Wv = (const float*)d_in[7];
    const float* bv = (const float*)d_in[8];
    float* out = (float*)d_out;
    char* ws = (char*)d_ws;

    // Workspace (bytes): [0,50331648) Xq,Xk,Xv contiguous; [50331648,56623104)
    // Wqh,Wkh,Wvh contiguous; region reused for fp16 scores after projections.
    // [73400320) Qh,Kh contiguous (reused for attn). [106954752) Vt.
    _Float16* Xq  = (_Float16*)(ws + 0);
    _Float16* Wqh = (_Float16*)(ws + 3 * XSZ * 2);
    _Float16* scores = (_Float16*)(ws + 0);
    _Float16* Qh  = (_Float16*)(ws + 73400320);
    _Float16* attn = (_Float16*)(ws + 73400320);
    _Float16* Vt  = (_Float16*)(ws + 106954752);
    if (ws_size < 123731968) return;

    // 1) convert inputs + weights to fp16 (contiguous destinations)
    cvt3_f32_f16<<<dim3(XSZ / 2048, 3), 256, 0, stream>>>(
        query, key, value, Xq, Xq + XSZ, Xq + 2 * XSZ, (int)XSZ);
    cvt3_f32_f16<<<dim3(WSZ / 2048, 3), 256, 0, stream>>>(
        Wq, Wk, Wv, Wqh, Wqh + WSZ, Wqh + 2 * WSZ, (int)WSZ);

    // 2) merged projections: per tensor M=8192 (64 y), N=1024 (8 x), K=1024.
    //    row_ids = 3*64=192, grid = 8*192 = 1536, R = 192/8 = 24.
    gemm_nt<1024, 3, 24, 6, true, true, true><<<1536, 256, 0, stream>>>(
        Xq, Wqh, bq, bk, bv, Qh, Vt, C, 1.0f, 0, 0, 0);

    // 3) scores = Qh @ Kh^T / 32, fp16 out. 16 x-tiles, 16 y, z=4 -> grid 1024, R=8.
    gemm_nt<1024, 4, 8, 4, false, true, false><<<1024, 256, 0, stream>>>(
        Qh, Qh + XSZ, nullptr, nullptr, nullptr, scores, nullptr, S, 0.03125f,
        (long)S * C, (long)S * C, (long)S * S);

    // 4) row softmax (fp16 in/out)
    softmax_f16<<<B * S, 256, 0, stream>>>(scores, attn);

    // 5) out = attn @ Vt^T. 8 x-tiles, 16 y, z=4 -> grid 512, R=8. fp32 out.
    gemm_nt<2048, 3, 8, 4, false, false, false><<<512, 256, 0, stream>>>(
        attn, Vt, nullptr, nullptr, nullptr, out, nullptr, C, 1.0f,
        (long)S * S, (long)C * S, (long)S * C);
}